// Round 6
// baseline (3402.939 us; speedup 1.0000x reference)
//
#include <hip/hip_runtime.h>

// NDDE forward-Euler, d=512, N=2000 — latency-bound on the per-step x
// all-to-all. R6 = R5 (agent/MALL exchange, wave-private y history) + a
// SELF-TESTED same-XCD fast path:
//   - 512 single-wave WGs launched; per-XCD arrival counters (agent atomics)
//     elect 64 waves on the first XCD to seat 64. Losers exit.
//   - Self-test: each elected wave sc0-STORES a tagged token, all waves
//     sc0-LOAD all 64 tokens (the exact op pair the fast loop uses). Result
//     aggregated via agent atomics; rank0 publishes GO/NOGO; modes never mix.
//   - GO: ring exchange via sc0 store -> sc0 load in the shared XCD L2
//     (~200cyc RTT vs ~700 at the MALL). NOGO: R5's agent path unchanged.
//   - y = x_{j-100} from wave-private history (plain ops, off critical path).
//   - No static LDS (R3's silent launch-fail lesson: 64KB/WG cap).

#define D     512
#define NTAU  100
#define M     112
#define HSLOT 101
#define NW    64          // working waves; wave w owns rows 8w..8w+7
#define NLAUNCH 512

typedef unsigned long long u64;

__device__ __forceinline__ float lo_f(u64 v){ union{unsigned u; float f;} c; c.u=(unsigned)v; return c.f; }
__device__ __forceinline__ u64 pack_rec(unsigned tag, float x){ union{unsigned u; float f;} c; c.f=x; return ((u64)tag<<32)|(u64)c.u; }

__device__ __forceinline__ u64 ag_ld(const u64* p){
    return __hip_atomic_load(p, __ATOMIC_RELAXED, __HIP_MEMORY_SCOPE_AGENT);
}
__device__ __forceinline__ void ag_st(u64* p, u64 v){
    __hip_atomic_store(p, v, __ATOMIC_RELAXED, __HIP_MEMORY_SCOPE_AGENT);
}
__device__ __forceinline__ int ag_ldi(const int* p){
    return __hip_atomic_load(p, __ATOMIC_RELAXED, __HIP_MEMORY_SCOPE_AGENT);
}
__device__ __forceinline__ u64 ld1_fast(const u64* p){
    u64 r;
    asm volatile("global_load_dwordx2 %0, %1, off sc0\n\ts_waitcnt vmcnt(0)"
                 : "=&v"(r) : "v"(p) : "memory");
    return r;
}

template<bool FAST>
__device__ __forceinline__ void rld8(const u64* p, u64 r[8]){
    if (FAST){
        asm volatile(
            "global_load_dwordx2 %0, %8, off sc0\n\t"
            "global_load_dwordx2 %1, %8, off offset:512 sc0\n\t"
            "global_load_dwordx2 %2, %8, off offset:1024 sc0\n\t"
            "global_load_dwordx2 %3, %8, off offset:1536 sc0\n\t"
            "global_load_dwordx2 %4, %8, off offset:2048 sc0\n\t"
            "global_load_dwordx2 %5, %8, off offset:2560 sc0\n\t"
            "global_load_dwordx2 %6, %8, off offset:3072 sc0\n\t"
            "global_load_dwordx2 %7, %8, off offset:3584 sc0\n\t"
            "s_waitcnt vmcnt(0)"
            : "=&v"(r[0]), "=&v"(r[1]), "=&v"(r[2]), "=&v"(r[3]),
              "=&v"(r[4]), "=&v"(r[5]), "=&v"(r[6]), "=&v"(r[7])
            : "v"(p) : "memory");
    } else {
        #pragma unroll
        for (int i = 0; i < 8; ++i) r[i] = ag_ld(p + 64 * i);
    }
}
template<bool FAST>
__device__ __forceinline__ void st_rec(u64* p, u64 v){
    if (FAST)
        asm volatile("global_store_dwordx2 %0, %1, off sc0" :: "v"(p), "v"(v) : "memory");
    else
        ag_st(p, v);
}
__device__ __forceinline__ float sel8(const float* a, int k){
    float s = a[0];
    s = (k == 1) ? a[1] : s;  s = (k == 2) ? a[2] : s;
    s = (k == 3) ? a[3] : s;  s = (k == 4) ? a[4] : s;
    s = (k == 5) ? a[5] : s;  s = (k == 6) ? a[6] : s;
    s = (k == 7) ? a[7] : s;
    return s;
}

template<bool FAST>
__device__ __forceinline__ void run_loop(
    int N, float dt, int lane, int rowbase,
    float (&w1v)[8][8], float (&w2v)[8][8],
    float (&yp)[8], float (&a)[8], float xloc, float bval,
    u64* ring, float* myh, int use_hist, float* out)
{
    u64 xr[8];
    float xf[8];
    int sx = 1, sp = 2, syr = 1;
    int hw = 0, hr = 0;
    bool dead = false;

    for (int j = 1; j < N && !dead; ++j){
        const bool needy  = (j > NTAU);
        const unsigned tx = (unsigned)(j + 1);
        const u64* px = ring + (size_t)sx * D + lane;

        u64 yr[8];
        if (!use_hist && needy){
            const u64* py = ring + (size_t)syr * D + lane;
            rld8<FAST>(py, yr);
        }

        // ---- spin for x_j ----
        int it = 0;
        for (;;){
            rld8<FAST>(px, xr);
            bool ok = true;
            #pragma unroll
            for (int i = 0; i < 8; ++i) ok &= ((unsigned)(xr[i] >> 32) == tx);
            if (__all(ok)) break;
            if (++it > (1 << 21)){ dead = true; break; }
        }
        #pragma unroll
        for (int i = 0; i < 8; ++i) xf[i] = lo_f(xr[i]);

        if (!use_hist && needy){
            const unsigned ty = (unsigned)(j - NTAU + 1);
            bool ok = true;
            #pragma unroll
            for (int i = 0; i < 8; ++i) ok &= ((unsigned)(yr[i] >> 32) == ty);
            if (!__all(ok)){
                const u64* py = ring + (size_t)syr * D + lane;
                int it2 = 0;
                for (;;){
                    rld8<FAST>(py, yr);
                    bool ok2 = true;
                    #pragma unroll
                    for (int i = 0; i < 8; ++i) ok2 &= ((unsigned)(yr[i] >> 32) == ty);
                    if (__all(ok2)) break;
                    if (++it2 > (1 << 21)){ dead = true; break; }
                }
            }
            #pragma unroll
            for (int r = 0; r < 8; ++r){
                float sy = 0.f;
                #pragma unroll
                for (int i = 0; i < 8; ++i) sy = fmaf(w2v[r][i], lo_f(yr[i]), sy);
                yp[r] = sy;
            }
        }

        // ---- critical path: 64 FMA + butterfly + integrate + publish ----
        #pragma unroll
        for (int r = 0; r < 8; ++r){
            float s = yp[r];
            #pragma unroll
            for (int i = 0; i < 8; ++i) s = fmaf(w1v[r][i], xf[i], s);
            a[r] = s;
        }
        #pragma unroll
        for (int off = 32; off >= 1; off >>= 1){
            #pragma unroll
            for (int r = 0; r < 8; ++r) a[r] += __shfl_xor(a[r], off, 64);
        }
        if (lane < 8){
            const float xn = xloc + dt * tanhf(sel8(a, lane) + bval);
            xloc = xn;
            const int row = rowbase + lane;
            st_rec<FAST>(ring + (size_t)sp * D + row, pack_rec(tx + 1, xn));
            out[(size_t)row * (N + 1) + (j + 1)] = xn;
        }

        // ---- post-publish shadow: history write + next-step y partial ----
        if (use_hist){
            float* hwp = myh + (size_t)hw * D + lane;
            #pragma unroll
            for (int i = 0; i < 8; ++i) hwp[64 * i] = xf[i];
            if (j >= NTAU){
                const float* hrp = myh + (size_t)hr * D + lane;
                float yv[8];
                #pragma unroll
                for (int i = 0; i < 8; ++i) yv[i] = hrp[64 * i];
                #pragma unroll
                for (int r = 0; r < 8; ++r){
                    float sy = 0.f;
                    #pragma unroll
                    for (int i = 0; i < 8; ++i) sy = fmaf(w2v[r][i], yv[i], sy);
                    yp[r] = sy;
                }
                hr = (hr == HSLOT - 1) ? 0 : hr + 1;
            }
            hw = (hw == HSLOT - 1) ? 0 : hw + 1;
        }

        sx = (sx == M - 1) ? 0 : sx + 1;
        sp = (sp == M - 1) ? 0 : sp + 1;
        if (j >= NTAU + 1) syr = (syr == M - 1) ? 0 : syr + 1;
    }
}

__global__ __launch_bounds__(64, 1) void ndde_r6(
    const float* __restrict__ x0p, const float* __restrict__ taup,
    const float* __restrict__ W1,  const float* __restrict__ W2,
    const float* __restrict__ bb,  const int* __restrict__ Np,
    float* __restrict__ out, int* __restrict__ ectl,
    u64* __restrict__ ring, float* __restrict__ hist, int use_hist)
{
    const int lane = threadIdx.x & 63;

    // ---- election: first XCD to seat NW single-wave WGs wins ----
    int xcd;
    asm("s_getreg_b32 %0, hwreg(HW_REG_XCC_ID, 0, 4)" : "=s"(xcd));
    xcd &= 7;
    int rank = -1;
    if (lane == 0){
        int r = __hip_atomic_fetch_add(&ectl[8 + xcd], 1, __ATOMIC_RELAXED, __HIP_MEMORY_SCOPE_AGENT);
        if (r < NW){
            if (r == NW - 1){
                int expv = 0;
                __hip_atomic_compare_exchange_strong(&ectl[0], &expv, xcd + 1,
                    __ATOMIC_RELAXED, __ATOMIC_RELAXED, __HIP_MEMORY_SCOPE_AGENT);
            }
            int w, g = 1 << 22;
            do { w = ag_ldi(&ectl[0]); } while (w == 0 && --g);
            if (w == xcd + 1) rank = r;
        }
    }
    rank = __shfl(rank, 0, 64);
    if (rank < 0) return;

    // ---- self-test the fast channel: sc0 store -> sc0 load, 64 tokens ----
    u64* tst = (u64*)((char*)ectl + 1024);
    if (lane == 0){
        u64 tok = pack_rec(0x7E570000u | (unsigned)rank, 3.f);
        asm volatile("global_store_dwordx2 %0, %1, off sc0" :: "v"(tst + rank), "v"(tok) : "memory");
    }
    bool myok = false;
    for (int it = 0; it < 8192; ++it){
        const u64 v = ld1_fast(tst + lane);
        const bool ok = ((unsigned)(v >> 32)) == (0x7E570000u | (unsigned)lane);
        if (__all(ok)){ myok = true; break; }
    }
    int dec = 0;
    if (lane == 0){
        if (myok) __hip_atomic_fetch_add(&ectl[33], 1, __ATOMIC_RELAXED, __HIP_MEMORY_SCOPE_AGENT);
        __hip_atomic_fetch_add(&ectl[32], 1, __ATOMIC_RELAXED, __HIP_MEMORY_SCOPE_AGENT);
        if (rank == 0){
            int dn, g = 1 << 22;
            do { dn = ag_ldi(&ectl[32]); } while (dn < NW && --g);
            const int oc = ag_ldi(&ectl[33]);
            __hip_atomic_store(&ectl[34], (dn == NW && oc == NW) ? 1 : 2,
                               __ATOMIC_RELAXED, __HIP_MEMORY_SCOPE_AGENT);
        }
        int g2 = 1 << 22;
        do { dec = ag_ldi(&ectl[34]); } while (dec == 0 && --g2);
    }
    dec = __shfl(dec, 0, 64);
    const bool go = (dec == 1);

    // ---- weights into VGPRs: 8 rows x 8 strided cols ----
    const int rowbase = rank * 8;
    const int N       = Np[0];
    const float dt    = 0.01f * taup[0];

    float w1v[8][8], w2v[8][8];
    #pragma unroll
    for (int r = 0; r < 8; ++r){
        const float* p1 = W1 + (size_t)(rowbase + r) * D + lane;
        const float* p2 = W2 + (size_t)(rowbase + r) * D + lane;
        #pragma unroll
        for (int i = 0; i < 8; ++i){
            w1v[r][i] = p1[64 * i];
            w2v[r][i] = p2[64 * i];
        }
    }
    #pragma unroll
    for (int r = 0; r < 8; ++r){
        #pragma unroll
        for (int i = 0; i < 8; ++i)
            asm volatile("" : "+v"(w1v[r][i]), "+v"(w2v[r][i]));
    }

    // ---- x0 partials; step 0 local; publish x_1 (mode store) ----
    float xv0[8];
    #pragma unroll
    for (int i = 0; i < 8; ++i) xv0[i] = x0p[64 * i + lane];
    float yp[8], a[8];
    #pragma unroll
    for (int r = 0; r < 8; ++r){
        float sy = 0.f, st = 0.f;
        #pragma unroll
        for (int i = 0; i < 8; ++i){
            sy = fmaf(w2v[r][i], xv0[i], sy);
            st = fmaf(w1v[r][i], xv0[i], st);
        }
        yp[r] = sy; a[r] = st + sy;
    }
    #pragma unroll
    for (int off = 32; off >= 1; off >>= 1){
        #pragma unroll
        for (int r = 0; r < 8; ++r) a[r] += __shfl_xor(a[r], off, 64);
    }

    float xloc = 0.f, bval = 0.f;
    if (lane < 8){
        const int row = rowbase + lane;
        xloc = x0p[row];
        bval = bb[row];
        out[(size_t)row * (N + 1)] = xloc;
        if (N >= 1){
            const float x1 = xloc + dt * tanhf(sel8(a, lane) + bval);
            xloc = x1;
            if (go) st_rec<true >(ring + D + row, pack_rec(2u, x1));
            else    st_rec<false>(ring + D + row, pack_rec(2u, x1));
            out[(size_t)row * (N + 1) + 1] = x1;
        }
    }

    float* myh = hist + (size_t)rank * HSLOT * D;
    if (go) run_loop<true >(N, dt, lane, rowbase, w1v, w2v, yp, a, xloc, bval, ring, myh, use_hist, out);
    else    run_loop<false>(N, dt, lane, rowbase, w1v, w2v, yp, a, xloc, bval, ring, myh, use_hist, out);
}

extern "C" void kernel_launch(void* const* d_in, const int* in_sizes, int n_in,
                              void* d_out, int out_size, void* d_ws, size_t ws_size,
                              hipStream_t stream)
{
    const float* x0  = (const float*)d_in[0];
    const float* tau = (const float*)d_in[1];
    const float* W1  = (const float*)d_in[2];
    const float* W2  = (const float*)d_in[3];
    const float* b   = (const float*)d_in[4];
    const int*   Np  = (const int*)  d_in[5];

    // d_ws: [0,4096) ectl (zeroed); ring M*D*8; history NW*HSLOT*D*4.
    const size_t ring_off   = 4096;
    const size_t ring_bytes = (size_t)M * D * 8;
    const size_t hist_bytes = (size_t)NW * HSLOT * D * 4;
    const int use_hist = (ws_size >= ring_off + ring_bytes + hist_bytes) ? 1 : 0;

    hipMemsetAsync(d_ws, 0, 4096, stream);
    int*   ectl = (int*)d_ws;
    u64*   ring = (u64*)((char*)d_ws + ring_off);
    float* hist = (float*)((char*)d_ws + ring_off + ring_bytes);

    hipLaunchKernelGGL(ndde_r6, dim3(NLAUNCH), dim3(64), 0, stream,
                       x0, tau, W1, W2, b, Np, (float*)d_out, ectl, ring, hist, use_hist);
}

// Round 7
// 2911.989 us; speedup vs baseline: 1.1686x; 1.1686x over previous
//
#include <hip/hip_runtime.h>

// NDDE forward-Euler, d=512, N=2000 — latency-bound on the per-step x
// all-to-all through the MALL (agent-scope atomics, the only HW-verified
// coherent channel: R1/R4/R5). R7 = R5 with three critical-path cuts:
//   1. amdgpu_waves_per_eu(1,1): 512-VGPR budget so the 128 weight floats
//      per lane are truly register-resident (R5's VGPR=104 + FETCH=40MB
//      proved the compiler was re-fetching weights every step).
//   2. Reduction: 3 low-bit butterfly levels on 8 accs (24 shfl) -> reg
//      select by lane&7 (7 cndmask) -> 3 high-bit levels on 1 reg (3 shfl).
//      Lane r ends with row r's total (was 48 shfl + sel8).
//   3. Depth-2 pipelined poll: batch B in flight while checking batch A.
// Same-XCD/sc0 fast paths abandoned (R2/R6: no reliable win, straggler risk).

#define D     512
#define NTAU  100
#define M     112        // ring depth > delay span 101 + skew
#define HSLOT 101        // wave-private history depth
#define NW    64         // waves; wave w owns rows 8w..8w+7

typedef unsigned long long u64;

__device__ __forceinline__ float lo_f(u64 v){ union{unsigned u; float f;} c; c.u=(unsigned)v; return c.f; }
__device__ __forceinline__ u64 pack_rec(unsigned tag, float x){ union{unsigned u; float f;} c; c.f=x; return ((u64)tag<<32)|(u64)c.u; }
__device__ __forceinline__ u64 ag_ld(const u64* p){
    return __hip_atomic_load(p, __ATOMIC_RELAXED, __HIP_MEMORY_SCOPE_AGENT);
}
__device__ __forceinline__ void ag_st(u64* p, u64 v){
    __hip_atomic_store(p, v, __ATOMIC_RELAXED, __HIP_MEMORY_SCOPE_AGENT);
}
__device__ __forceinline__ void iss8(const u64* p, u64 r[8]){
    #pragma unroll
    for (int i = 0; i < 8; ++i) r[i] = ag_ld(p + 64 * i);
}
__device__ __forceinline__ bool chk8(const u64 r[8], unsigned t){
    bool ok = true;
    #pragma unroll
    for (int i = 0; i < 8; ++i) ok &= ((unsigned)(r[i] >> 32) == t);
    return __all(ok);
}
// select a[k], k in 0..7, without dynamic indexing (cmps hoisted: k loop-inv)
__device__ __forceinline__ float sel8(const float* a, int k){
    float s = a[0];
    s = (k == 1) ? a[1] : s;  s = (k == 2) ? a[2] : s;
    s = (k == 3) ? a[3] : s;  s = (k == 4) ? a[4] : s;
    s = (k == 5) ? a[5] : s;  s = (k == 6) ? a[6] : s;
    s = (k == 7) ? a[7] : s;
    return s;
}

__global__ __launch_bounds__(64)
__attribute__((amdgpu_waves_per_eu(1, 1)))
void ndde_r7(
    const float* __restrict__ x0p, const float* __restrict__ taup,
    const float* __restrict__ W1,  const float* __restrict__ W2,
    const float* __restrict__ bb,  const int* __restrict__ Np,
    float* __restrict__ out, u64* __restrict__ ring,
    float* __restrict__ hist, int use_hist)
{
    const int lane    = threadIdx.x & 63;
    const int wb      = blockIdx.x;          // 0..63
    const int rowbase = wb * 8;
    const int N       = Np[0];
    const float dt    = 0.01f * taup[0];

    // ---- weights: 8 rows x 8 strided cols (col = 64*i + lane) ----
    float w1v[8][8], w2v[8][8];
    #pragma unroll
    for (int r = 0; r < 8; ++r){
        const float* p1 = W1 + (size_t)(rowbase + r) * D + lane;
        const float* p2 = W2 + (size_t)(rowbase + r) * D + lane;
        #pragma unroll
        for (int i = 0; i < 8; ++i){
            w1v[r][i] = p1[64 * i];
            w2v[r][i] = p2[64 * i];
        }
    }

    // ---- x0 partials: yp = W2*x0 (reused for all j <= 100) ----
    float xv0[8];
    #pragma unroll
    for (int i = 0; i < 8; ++i) xv0[i] = x0p[64 * i + lane];
    float yp[8], a[8];
    #pragma unroll
    for (int r = 0; r < 8; ++r){
        float sy = 0.f, st = 0.f;
        #pragma unroll
        for (int i = 0; i < 8; ++i){
            sy = fmaf(w2v[r][i], xv0[i], sy);
            st = fmaf(w1v[r][i], xv0[i], st);
        }
        yp[r] = sy; a[r] = st + sy;
    }

    // ---- reduction: low-bit butterfly -> reg select -> high-bit butterfly ----
    const int sel = lane & 7;
    #pragma unroll
    for (int r = 0; r < 8; ++r){
        a[r] += __shfl_xor(a[r], 1, 64);
        a[r] += __shfl_xor(a[r], 2, 64);
        a[r] += __shfl_xor(a[r], 4, 64);
    }
    float d0 = sel8(a, sel);
    d0 += __shfl_xor(d0, 8, 64);
    d0 += __shfl_xor(d0, 16, 64);
    d0 += __shfl_xor(d0, 32, 64);
    // lane r (r<8) now holds row rowbase+r's full dot for step 0

    // ---- step 0 local; publish x_1 (tag 2) into ring slot 1 ----
    float xloc = 0.f, bval = 0.f;
    if (lane < 8){
        const int row = rowbase + lane;
        xloc = x0p[row];
        bval = bb[row];
        out[(size_t)row * (N + 1)] = xloc;
        if (N >= 1){
            const float x1 = xloc + dt * tanhf(d0 + bval);
            xloc = x1;
            ag_st(ring + D + row, pack_rec(2u, x1));
            out[(size_t)row * (N + 1) + 1] = x1;
        }
    }

    float* myh = hist + (size_t)wb * HSLOT * D;   // wave-private history

    u64 xa[8], xb[8];
    float xf[8];
    int sx = 1, sp = 2, syr = 1;   // ring slots: j%M, (j+1)%M, (j-100)%M
    int hw = 0, hr = 0;            // history write/read slots
    bool dead = false;

    for (int j = 1; j < N && !dead; ++j){
        const bool needy  = (j > NTAU);
        const unsigned tx = (unsigned)(j + 1);
        const u64* px = ring + (size_t)sx * D + lane;

        // ---- fallback path only: agent y before the x-spin ----
        u64 yr[8];
        if (!use_hist && needy){
            const u64* py = ring + (size_t)syr * D + lane;
            iss8(py, yr);
        }

        // ---- depth-2 pipelined spin for x_j ----
        iss8(px, xa);
        int it = 0;
        for (;;){
            iss8(px, xb);
            if (chk8(xa, tx)) break;
            iss8(px, xa);
            if (chk8(xb, tx)){
                #pragma unroll
                for (int i = 0; i < 8; ++i) xa[i] = xb[i];
                break;
            }
            if ((it += 2) > (1 << 21)){ dead = true; break; }
        }
        #pragma unroll
        for (int i = 0; i < 8; ++i) xf[i] = lo_f(xa[i]);

        // ---- fallback path only: verify y, recompute yp on mismatch ----
        if (!use_hist && needy){
            const unsigned ty = (unsigned)(j - NTAU + 1);
            if (!chk8(yr, ty)){
                const u64* py = ring + (size_t)syr * D + lane;
                int it2 = 0;
                for (;;){
                    iss8(py, yr);
                    if (chk8(yr, ty)) break;
                    if (++it2 > (1 << 21)){ dead = true; break; }
                }
            }
            #pragma unroll
            for (int r = 0; r < 8; ++r){
                float sy = 0.f;
                #pragma unroll
                for (int i = 0; i < 8; ++i) sy = fmaf(w2v[r][i], lo_f(yr[i]), sy);
                yp[r] = sy;
            }
        }

        // ---- critical path: 64 FMA + 34-op reduction + integrate + publish ----
        #pragma unroll
        for (int r = 0; r < 8; ++r){
            float s = yp[r];
            #pragma unroll
            for (int i = 0; i < 8; ++i) s = fmaf(w1v[r][i], xf[i], s);
            a[r] = s;
        }
        #pragma unroll
        for (int r = 0; r < 8; ++r){
            a[r] += __shfl_xor(a[r], 1, 64);
            a[r] += __shfl_xor(a[r], 2, 64);
            a[r] += __shfl_xor(a[r], 4, 64);
        }
        float dd = sel8(a, sel);
        dd += __shfl_xor(dd, 8, 64);
        dd += __shfl_xor(dd, 16, 64);
        dd += __shfl_xor(dd, 32, 64);

        if (lane < 8){
            const float xn = xloc + dt * tanhf(dd + bval);
            xloc = xn;
            const int row = rowbase + lane;
            ag_st(ring + (size_t)sp * D + row, pack_rec(tx + 1, xn));
            out[(size_t)row * (N + 1) + (j + 1)] = xn;
        }

        // ---- post-publish shadow: history write + next-step y partial ----
        if (use_hist){
            float* hwp = myh + (size_t)hw * D + lane;
            #pragma unroll
            for (int i = 0; i < 8; ++i) hwp[64 * i] = xf[i];
            if (j >= NTAU){            // step j+1 needs y = x_{j-99}
                const float* hrp = myh + (size_t)hr * D + lane;
                float yv[8];
                #pragma unroll
                for (int i = 0; i < 8; ++i) yv[i] = hrp[64 * i];
                #pragma unroll
                for (int r = 0; r < 8; ++r){
                    float sy = 0.f;
                    #pragma unroll
                    for (int i = 0; i < 8; ++i) sy = fmaf(w2v[r][i], yv[i], sy);
                    yp[r] = sy;
                }
                hr = (hr == HSLOT - 1) ? 0 : hr + 1;
            }
            hw = (hw == HSLOT - 1) ? 0 : hw + 1;
        }

        sx = (sx == M - 1) ? 0 : sx + 1;
        sp = (sp == M - 1) ? 0 : sp + 1;
        if (j >= NTAU + 1) syr = (syr == M - 1) ? 0 : syr + 1;
    }
}

extern "C" void kernel_launch(void* const* d_in, const int* in_sizes, int n_in,
                              void* d_out, int out_size, void* d_ws, size_t ws_size,
                              hipStream_t stream)
{
    const float* x0  = (const float*)d_in[0];
    const float* tau = (const float*)d_in[1];
    const float* W1  = (const float*)d_in[2];
    const float* W2  = (const float*)d_in[3];
    const float* b   = (const float*)d_in[4];
    const int*   Np  = (const int*)  d_in[5];

    // d_ws layout: ring [0, M*D*8); wave-private history after.
    // No memset needed: ring tags are 1..N+1; 0xAA poison never matches.
    const size_t ring_bytes = (size_t)M * D * 8;
    const size_t hist_bytes = (size_t)NW * HSLOT * D * 4;
    const int use_hist = (ws_size >= ring_bytes + hist_bytes) ? 1 : 0;

    u64*   ring = (u64*)d_ws;
    float* hist = (float*)((char*)d_ws + ring_bytes);

    hipLaunchKernelGGL(ndde_r7, dim3(NW), dim3(64), 0, stream,
                       x0, tau, W1, W2, b, Np, (float*)d_out, ring, hist, use_hist);
}